// Round 24
// baseline (64.381 us; speedup 1.0000x reference)
//
#include <hip/hip_runtime.h>
#include <utility>

#define D_DIM 256
#define WID   33
#define CEN   16
#define RACC  8                    // output rows per thread
#define XROWS (RACC + 2 * CEN)     // 40 x-rows streamed per thread
#define RITER 16                   // output rows per iteration
#define NI    16                   // iterations per block
#define CHUNK (RITER * NI)         // 256 output rows per block
#define RING  64                   // ring rows = 64 KB LDS
#define PROL  48                   // prologue staged rows

// R23 (63.1us) post-mortem: per-iter __syncthreads drains vmcnt(0) -> waits
// for the 8 output stores + 9 weight loads too, a ~700cy serial bubble/iter
// with only 2 blocks/CU to hide it. T4 fix: counted wait. Ops younger than
// this iter's 4 DMAs are always >= 8 (the stores, pinned behind
// sched_barrier) -> s_waitcnt vmcnt(8) + raw s_barrier guarantees the DMAs
// landed while stores/weight-prefetch stay in flight across the barrier.

typedef float f32x2 __attribute__((ext_vector_type(2)));

__device__ __forceinline__ float rdlane(float v, int l) {
    return __uint_as_float(__builtin_amdgcn_readlane(__float_as_uint(v), l));
}

__device__ __forceinline__ int clampN(int p, int N) {
    return p < 0 ? 0 : (p >= N ? N - 1 : p);
}

__device__ __forceinline__ f32x2 ld2(const float* p) {
    return *(const f32x2*)p;
}

__device__ __forceinline__ void dma_row(float* xs, int slot,
                                        const float* __restrict__ xlane,
                                        int row) {
    __builtin_amdgcn_global_load_lds(
        (const __attribute__((address_space(1))) void*)(xlane +
                                                        (size_t)row * D_DIM),
        (__attribute__((address_space(3))) void*)(xs + slot * D_DIM), 16, 0, 0);
}

template <size_t... Ss>
__device__ __forceinline__ void stage_prol(float* xs,
                                           const float* __restrict__ xlane,
                                           int base0, int N, int wv,
                                           std::index_sequence<Ss...>) {
    (([&] {
         const int s = wv * (PROL / 4) + (int)Ss;
         dma_row(xs, s, xlane, clampN(base0 + s, N));
     }()),
     ...);
}

template <int PH, size_t... Ss>
__device__ __forceinline__ void stage_iter(float* xs,
                                           const float* __restrict__ xlane,
                                           int base0, int m, int N, int wv,
                                           std::index_sequence<Ss...>) {
    (([&] {
         constexpr int C = (PROL + 16 * PH) & (RING - 1);
         const int j = wv * 4 + (int)Ss;
         dma_row(xs, C + j, xlane, clampN(base0 + PROL + 16 * m + j, N));
     }()),
     ...);
}

template <size_t... Rs>
__device__ __forceinline__ void load_w(float (&w)[RACC],
                                       const float* __restrict__ smb,
                                       int nbase, int minl, int N,
                                       std::index_sequence<Rs...>) {
    ((w[Rs] = smb[(size_t)clampN(nbase + (int)Rs, N) * WID + minl]), ...);
}

template <size_t... Rs>
__device__ __forceinline__ void zero_bad_w(float (&w)[RACC], int n0w, int lane,
                                           int N, std::index_sequence<Rs...>) {
    ((w[Rs] = ((unsigned)(n0w + (int)Rs - CEN + lane) < (unsigned)N)
                  ? w[Rs] : 0.0f),
     ...);
}

template <int J, size_t... Rs>
__device__ __forceinline__ void consume_j(f32x2 (&acc)[RACC],
                                          const float (&w)[RACC], f32x2 xv,
                                          std::index_sequence<Rs...>) {
    (([&] {
         constexpr int r = (int)Rs;
         if constexpr (J - r >= 0 && J - r < WID) {
             const float ws = rdlane(w[r], J - r);
             acc[r].x = fmaf(xv.x, ws, acc[r].x);
             acc[r].y = fmaf(xv.y, ws, acc[r].y);
         }
     }()),
     ...);
}

template <int PH, int RG, size_t... Js>
__device__ __forceinline__ void stream_rows(f32x2 (&acc)[RACC],
                                            const float (&w)[RACC],
                                            const float* xscp,
                                            std::index_sequence<Js...>) {
    (([&] {
         constexpr int slot = (16 * PH + 8 * RG + (int)Js) & (RING - 1);
         const f32x2 xv = ld2(xscp + slot * D_DIM);
         consume_j<(int)Js>(acc, w, xv, std::make_index_sequence<RACC>{});
     }()),
     ...);
}

template <size_t... Rs>
__device__ __forceinline__ void store_all(const f32x2 (&acc)[RACC], float szv,
                                          float* __restrict__ ob,
                                          std::index_sequence<Rs...>) {
    (([&] {
         constexpr int r = (int)Rs;
         const float inv = __builtin_amdgcn_rcpf(fmaxf(rdlane(szv, r), 1e-6f));
         f32x2 o;
         o.x = acc[r].x * inv;
         o.y = acc[r].y * inv;
         *(f32x2*)(ob + (size_t)r * D_DIM) = o;
     }()),
     ...);
}

template <int PH>
__device__ __forceinline__ void iter_body(
    float* xs, const float* __restrict__ xlane, const float* __restrict__ smb,
    const float* __restrict__ szb, float* __restrict__ obcp, int n0, int m,
    int N, int wv, int rg, int lane, int cp, float (&wcur)[RACC],
    float (&wnxt)[RACC], float& szcur, float& sznxt, int minl) {
    // phase 1: issue next-tile DMA + next-iter weight/size prefetch
    if (m < NI - 1)
        stage_iter<PH>(xs, xlane, n0 - CEN, m, N, wv,
                       std::make_index_sequence<4>{});
    const int n1 = n0 + (m + 1) * RITER + rg * RACC;
    load_w(wnxt, smb, n1, minl, N, std::make_index_sequence<RACC>{});
    sznxt = szb[clampN(n1 + (lane & 7), N)];
    __builtin_amdgcn_sched_barrier(0);

    // phase 2: compute current 16 rows from the ring
    const int n0w = n0 + m * RITER + rg * RACC;
    if (n0w < CEN || n0w + RACC - 1 + CEN >= N)      // boundary iters only
        zero_bad_w(wcur, n0w, lane, N, std::make_index_sequence<RACC>{});

    f32x2 acc[RACC] = {};
    if (rg == 0)
        stream_rows<PH, 0>(acc, wcur, xs + cp, std::make_index_sequence<XROWS>{});
    else
        stream_rows<PH, 1>(acc, wcur, xs + cp, std::make_index_sequence<XROWS>{});

    store_all(acc, szcur, obcp + (size_t)n0w * D_DIM,
              std::make_index_sequence<RACC>{});

    // T4 counted barrier: wait only for this iter's 4 DMAs (the 8 stores are
    // always younger); stores + weight prefetch stay in flight.
    __builtin_amdgcn_sched_barrier(0);
    asm volatile("s_waitcnt vmcnt(8)" ::: "memory");
    __builtin_amdgcn_s_barrier();
    __builtin_amdgcn_sched_barrier(0);
}

__global__ __launch_bounds__(256) void local_enc_kernel(
    const float* __restrict__ x, const float* __restrict__ sizev,
    const float* __restrict__ sm, float* __restrict__ out, int N) {
    __shared__ float xs[RING * D_DIM];     // 64 rows x 1KB = 64 KB

    // XCD swizzle: XCD k owns batch k, strips consecutive -> L2-local
    const int bid   = blockIdx.x;
    const int swz   = (bid & 7) * 64 + (bid >> 3);
    const int strip = swz & 63;
    const int b     = swz >> 6;
    const int n0    = strip * CHUNK;
    const int tid   = threadIdx.x;
    const int wv    = tid >> 6;            // 0..3: 2 row-groups x 2 col-halves
    const int lane  = tid & 63;
    const int rg    = wv >> 1;
    const int cp    = ((wv & 1) * 64 + lane) * 2;

    const size_t bN = (size_t)b * (size_t)N;
    const float* __restrict__ xlane = x + bN * D_DIM + lane * 4;
    const float* __restrict__ smb   = sm + bN * WID;
    const float* __restrict__ szb   = sizev + bN;
    float* __restrict__ obcp        = out + bN * D_DIM + cp;

    // prologue: stage first 48 rows + load iter-0 weights/sizes
    stage_prol(xs, xlane, n0 - CEN, N, wv, std::make_index_sequence<PROL / 4>{});
    const int minl = (lane < WID) ? lane : (WID - 1);
    float wA[RACC], wB[RACC];
    float szA, szB;
    load_w(wA, smb, n0 + rg * RACC, minl, N, std::make_index_sequence<RACC>{});
    szA = szb[clampN(n0 + rg * RACC + (lane & 7), N)];
    __syncthreads();                       // one-time full drain is fine

#pragma unroll 1
    for (int mo = 0; mo < NI / 4; ++mo) {
        const int m0 = 4 * mo;
        iter_body<0>(xs, xlane, smb, szb, obcp, n0, m0 + 0, N, wv, rg, lane,
                     cp, wA, wB, szA, szB, minl);
        iter_body<1>(xs, xlane, smb, szb, obcp, n0, m0 + 1, N, wv, rg, lane,
                     cp, wB, wA, szB, szA, minl);
        iter_body<2>(xs, xlane, smb, szb, obcp, n0, m0 + 2, N, wv, rg, lane,
                     cp, wA, wB, szA, szB, minl);
        iter_body<3>(xs, xlane, smb, szb, obcp, n0, m0 + 3, N, wv, rg, lane,
                     cp, wB, wA, szB, szA, minl);
    }
}

extern "C" void kernel_launch(void* const* d_in, const int* in_sizes, int n_in,
                              void* d_out, int out_size, void* d_ws, size_t ws_size,
                              hipStream_t stream) {
    const float* x  = (const float*)d_in[0];
    const float* sz = (const float*)d_in[1];
    const float* sm = (const float*)d_in[2];
    float* out = (float*)d_out;

    const int B = 8;
    const int N = 16384;

    dim3 grid((N / CHUNK) * B, 1, 1);   // 64 x 8 = 512 blocks, XCD-swizzled
    dim3 block(256, 1, 1);
    local_enc_kernel<<<grid, block, 0, stream>>>(x, sz, sm, out, N);
}